// Round 15
// baseline (250.909 us; speedup 1.0000x reference)
//
#include <hip/hip_runtime.h>

typedef unsigned short u16;
typedef unsigned int u32;
typedef short s16x8 __attribute__((ext_vector_type(8)));
typedef float f32x4 __attribute__((ext_vector_type(4)));

// ---- constants for this problem ----
#define BB 8
#define SS 1024
#define EE 1024
#define HH 16
#define DD 64

__device__ inline u16 f2bf(float f) {
  union { float f; unsigned u; } x; x.f = f;
  unsigned r = x.u + 0x7fffu + ((x.u >> 16) & 1u);  // RNE
  return (u16)(r >> 16);
}
__device__ inline float bf2f(u16 u) {
  union { unsigned u; float f; } x; x.u = ((unsigned)u) << 16; return x.f;
}
// packed f32x2 -> bf16x2 via HW instruction (RNE), 1 VALU op
__device__ inline u32 cvtpk(float lo, float hi) {
  u32 r;
  asm("v_cvt_pk_bf16_f32 %0, %1, %2" : "=v"(r) : "v"(lo), "v"(hi));
  return r;
}

// ---------------- weight transpose+convert ----------------
__global__ __launch_bounds__(256) void transpose_w(
    const float* __restrict__ Wq, const float* __restrict__ Wk,
    const float* __restrict__ Wv, const float* __restrict__ Wo,
    u16* __restrict__ Wt3, u16* __restrict__ Wot)
{
  __shared__ float tile[64][65];
  int z = blockIdx.z;
  const float* src; u16* dst; int r0, c0, ldS, ldD;
  if (z < 3) {
    const float* W = (z == 0) ? Wq : (z == 1) ? Wk : Wv;
    int h = blockIdx.y;
    src = W + h * (EE * DD); r0 = blockIdx.x * 64; c0 = 0; ldS = DD;
    dst = Wt3 + z * (EE * EE) + h * 64 * EE; ldD = EE;
  } else {
    src = Wo; r0 = blockIdx.x * 64; c0 = blockIdx.y * 64; ldS = EE;
    dst = Wot; ldD = EE;
  }
  int t = threadIdx.x;
  int lr = t >> 2, lc = (t & 3) * 16;
#pragma unroll
  for (int i = 0; i < 16; i += 4) {
    float4 f = *(const float4*)(src + (size_t)(r0 + lr) * ldS + c0 + lc + i);
    tile[lr][lc + i] = f.x; tile[lr][lc + i + 1] = f.y;
    tile[lr][lc + i + 2] = f.z; tile[lr][lc + i + 3] = f.w;
  }
  __syncthreads();
#pragma unroll
  for (int i = 0; i < 16; i++)
    dst[(size_t)(c0 + lr) * ldD + r0 + lc + i] = f2bf(tile[lc + i][lr]);
}

// ---------------- pb -> bf16 table ----------------
__global__ __launch_bounds__(256) void pb2h(const float* __restrict__ pb,
                                            u16* __restrict__ pbh)
{
  int t = blockIdx.x * 256 + threadIdx.x;
  pbh[t] = f2bf(pb[t]);
}

// ---------------- f32 -> bf16 bulk convert (8 elems/thread) ----------------
__global__ __launch_bounds__(256) void f2h(const float* __restrict__ in,
                                           u16* __restrict__ out)
{
  int i = (blockIdx.x * 256 + threadIdx.x) * 8;
  float4 a = *(const float4*)(in + i);
  float4 b = *(const float4*)(in + i + 4);
  uint4 r;
  r.x = cvtpk(a.x, a.y); r.y = cvtpk(a.z, a.w);
  r.z = cvtpk(b.x, b.y); r.w = cvtpk(b.z, b.w);
  *(uint4*)(out + i) = r;
}

// ---------------- 128x128 bf16 GEMM: BK=64, BOTH operands via global_load_lds ----------------
// (r12-proven: ~690 TF on projections)
#define BK 64
__global__ __launch_bounds__(256, 2) void gemm128(
    const u16* __restrict__ At, const u16* __restrict__ Bt,
    const float* __restrict__ bias, void* __restrict__ out,
    int M, int N, int K, int mode)
{
  __shared__ __attribute__((aligned(16))) u16 As[128 * BK];
  __shared__ __attribute__((aligned(16))) u16 Bs[128 * BK];
  int t = threadIdx.x;
  int lane = t & 63, wid = t >> 6;
  int row0 = blockIdx.y * 128, col0 = blockIdx.x * 128;
  int wr = (wid >> 1) * 64, wc = (wid & 1) * 64;
  int lr = lane & 15, lg = lane >> 4;
  f32x4 acc[4][4];
#pragma unroll
  for (int m = 0; m < 4; m++)
#pragma unroll
    for (int n = 0; n < 4; n++)
      acc[m][n] = (f32x4){0.f, 0.f, 0.f, 0.f};

  int grow[4], gls[4];
#pragma unroll
  for (int j = 0; j < 4; j++) {
    int c = wid * 256 + j * 64 + lane;
    grow[j] = c >> 3;
    gls[j] = (c & 7) ^ (grow[j] & 7);
  }

  for (int k0 = 0; k0 < K; k0 += BK) {
    __syncthreads();
#pragma unroll
    for (int j = 0; j < 4; j++) {
      __builtin_amdgcn_global_load_lds(
          (const u32*)(At + (size_t)(row0 + grow[j]) * K + k0 + gls[j] * 8),
          (u32*)((char*)As + (wid * 256 + j * 64) * 16), 16, 0, 0);
      __builtin_amdgcn_global_load_lds(
          (const u32*)(Bt + (size_t)(col0 + grow[j]) * K + k0 + gls[j] * 8),
          (u32*)((char*)Bs + (wid * 256 + j * 64) * 16), 16, 0, 0);
    }
    __syncthreads();
#pragma unroll
    for (int kf = 0; kf < 2; kf++) {
      s16x8 af[4], bf[4];
#pragma unroll
      for (int m = 0; m < 4; m++) {
        int r = wr + m * 16 + lr;
        af[m] = *(const s16x8*)((char*)As + r * 128 + (((kf * 4 + lg) ^ (r & 7)) * 16));
      }
#pragma unroll
      for (int n = 0; n < 4; n++) {
        int r = wc + n * 16 + lr;
        bf[n] = *(const s16x8*)((char*)Bs + r * 128 + (((kf * 4 + lg) ^ (r & 7)) * 16));
      }
#pragma unroll
      for (int m = 0; m < 4; m++)
#pragma unroll
        for (int n = 0; n < 4; n++)
          acc[m][n] = __builtin_amdgcn_mfma_f32_16x16x32_bf16(af[m], bf[n], acc[m][n], 0, 0, 0);
    }
  }

#pragma unroll
  for (int n = 0; n < 4; n++) {
    int colb = col0 + wc + n * 16 + lr;
    float bv = bias[colb];
#pragma unroll
    for (int m = 0; m < 4; m++) {
#pragma unroll
      for (int v = 0; v < 4; v++) {
        int rowb = row0 + wr + m * 16 + lg * 4 + v;
        float val = acc[m][n][v] + bv;
        if (mode == 3) {
          ((float*)out)[(size_t)rowb * N + colb] = val;
        } else {
          int bb = rowb >> 10, s = rowb & 1023, hh = colb >> 6, dd = colb & 63;
          u16 u = f2bf(val);
          if (mode == 2)
            ((u16*)out)[(size_t)((bb * HH + hh) * DD + dd) * SS + s] = u;
          else
            ((u16*)out)[(size_t)((bb * HH + hh) * SS + s) * DD + dd] = u;
        }
      }
    }
  }
}

// ---------------- flash attention (v9: r12 body + double-buffered K/V, 1 barrier/tile) ----------------
// 1024 blocks x 256 threads. Decode: xcd = wgid&7, bh = xcd*16 + ((wgid>>3)&15),
// strip s = 7 - (wgid>>7). Block does 128 q rows, wave w owns rows q0b+32w..+32.
// T14 async-STAGE: per tile, issue next tile's global loads -> compute current
// (from LDS buf[cur]) -> swizzled ds_write next tile into buf[cur^1] -> ONE barrier.
// LDS: 2 x (K 8KB | V 8KB) dbuf + P 4KB/wave = 48KB (3 blocks/CU; VGPR growth free
// under the LDS bound). Softmax/PV body byte-identical to r12.
#define KVB 64
#define KS_OFF 0
#define VS_OFF 8192
#define BUF_STRIDE 16384
#define PW_OFF 32768

__global__ __launch_bounds__(256) void attn_k(
    const u16* __restrict__ qp, const u16* __restrict__ kp,
    const u16* __restrict__ vT, const u16* __restrict__ pbh,
    u16* __restrict__ attout)
{
  __shared__ __attribute__((aligned(16))) char lds[49152];
  int wgid = blockIdx.x;
  int bh = (wgid & 7) * 16 + ((wgid >> 3) & 15);
  int s8 = 7 - (wgid >> 7);
  int t = threadIdx.x;
  int lane = t & 63, wid = t >> 6;
  int lr = lane & 15, lg = lane >> 4;
  const char* Qb = (const char*)(qp + (size_t)bh * SS * DD);
  const char* Kb = (const char*)(kp + (size_t)bh * SS * DD);
  const char* Vb = (const char*)(vT + (size_t)bh * SS * DD);
  int b = bh >> 4, h = bh & 15;
  char* Pbase = lds + PW_OFF + wid * 4096;

  int q0b = s8 * 128;
  int q0 = q0b + wid * 32;
  int kv_end = q0 + 32;

  // staging address precompute (2 chunks/thread)
  int srow[2], scolb[2], ssw[2];
#pragma unroll
  for (int i = 0; i < 2; i++) {
    int c = i * 256 + t;
    srow[i] = c >> 3; scolb[i] = (c & 7) << 4; ssw[i] = (srow[i] & 7) << 4;
  }

  // Q fragments for this strip
  s16x8 qf[2][2];
#pragma unroll
  for (int m = 0; m < 2; m++)
#pragma unroll
    for (int kf = 0; kf < 2; kf++)
      qf[m][kf] = *(const s16x8*)(Qb + (size_t)(q0 + m * 16 + lr) * 128 + kf * 64 + lg * 16);

  f32x4 o[2][4];
  float mrun[2][4], lrun[2][4];
#pragma unroll
  for (int m = 0; m < 2; m++) {
#pragma unroll
    for (int n = 0; n < 4; n++) o[m][n] = (f32x4){0.f, 0.f, 0.f, 0.f};
#pragma unroll
    for (int v = 0; v < 4; v++) { mrun[m][v] = -1e30f; lrun[m][v] = 0.f; }
  }

  int ntiles = (q0b + 128) / KVB;

  // prologue: stage tile 0 into buf 0
#pragma unroll
  for (int i = 0; i < 2; i++) {
    uint4 kd = *(const uint4*)(Kb + (size_t)srow[i] * 128 + scolb[i]);
    uint4 vd = *(const uint4*)(Vb + (size_t)srow[i] * 2048 + scolb[i]);
    *(uint4*)(lds + KS_OFF + srow[i] * 128 + (scolb[i] ^ ssw[i])) = kd;
    *(uint4*)(lds + VS_OFF + srow[i] * 128 + (scolb[i] ^ ssw[i])) = vd;
  }
  __syncthreads();

  int cur = 0;
  for (int ti = 0; ti < ntiles; ti++) {
    int kv0 = ti * KVB;
    bool pref = (ti + 1 < ntiles);   // block-uniform
    uint4 kd[2], vd[2];
    if (pref) {
      int kvn = kv0 + KVB;
#pragma unroll
      for (int i = 0; i < 2; i++) {
        kd[i] = *(const uint4*)(Kb + (size_t)(kvn + srow[i]) * 128 + scolb[i]);
        vd[i] = *(const uint4*)(Vb + (size_t)srow[i] * 2048 + (size_t)kvn * 2 + scolb[i]);
      }
    }

    const char* Kcur = lds + cur * BUF_STRIDE + KS_OFF;
    const char* Vcur = lds + cur * BUF_STRIDE + VS_OFF;

    if (kv0 < kv_end) {
      // --- QK^T from LDS ---
      f32x4 s[2][4];
#pragma unroll
      for (int tt = 0; tt < 4; tt++) {
        int r = tt * 16 + lr;
        int sw = (r & 7) << 4;
        s16x8 k0 = *(const s16x8*)(Kcur + (((r << 7) + lg * 16) ^ sw));
        s16x8 k1 = *(const s16x8*)(Kcur + (((r << 7) + 64 + lg * 16) ^ sw));
#pragma unroll
        for (int m = 0; m < 2; m++) {
          f32x4 acc = (f32x4){0.f, 0.f, 0.f, 0.f};
          acc = __builtin_amdgcn_mfma_f32_16x16x32_bf16(qf[m][0], k0, acc, 0, 0, 0);
          acc = __builtin_amdgcn_mfma_f32_16x16x32_bf16(qf[m][1], k1, acc, 0, 0, 0);
          s[m][tt] = acc;
        }
      }
      bool full = (kv0 + KVB - 1 <= q0);
      // --- scale + bias + causal + online softmax (one-pass, __expf) ---
#pragma unroll
      for (int m = 0; m < 2; m++) {
#pragma unroll
        for (int v = 0; v < 4; v++) {
          int qq = q0 + m * 16 + lg * 4 + v;
          const u16* pbrow = pbh + (size_t)qq * SS + kv0 + lr;
          float sv[4];
#pragma unroll
          for (int tt = 0; tt < 4; tt++) {
            float bi = bf2f(pbrow[tt * 16]);
            float x = fmaf(s[m][tt][v], 0.125f, bi);
            if (!full && (kv0 + tt * 16 + lr > qq)) x = -1e30f;
            sv[tt] = x;
          }
          float mt = fmaxf(fmaxf(sv[0], sv[1]), fmaxf(sv[2], sv[3]));
          mt = fmaxf(mt, __shfl_xor(mt, 1));
          mt = fmaxf(mt, __shfl_xor(mt, 2));
          mt = fmaxf(mt, __shfl_xor(mt, 4));
          mt = fmaxf(mt, __shfl_xor(mt, 8));
          float mn = fmaxf(mrun[m][v], mt);
          float corr = __expf(mrun[m][v] - mn);
          float p0 = __expf(sv[0] - mn);
          float p1 = __expf(sv[1] - mn);
          float p2 = __expf(sv[2] - mn);
          float p3 = __expf(sv[3] - mn);
          float rs = (p0 + p1) + (p2 + p3);
          rs += __shfl_xor(rs, 1);
          rs += __shfl_xor(rs, 2);
          rs += __shfl_xor(rs, 4);
          rs += __shfl_xor(rs, 8);
          lrun[m][v] = lrun[m][v] * corr + rs;
          mrun[m][v] = mn;
#pragma unroll
          for (int n = 0; n < 4; n++) o[m][n][v] *= corr;
          int qrow = m * 16 + lg * 4 + v;
          int rb = qrow * 128;
          int sw = (qrow & 7) << 4;
          *(u16*)(Pbase + ((rb + (lr * 2)) ^ sw))       = f2bf(p0);
          *(u16*)(Pbase + ((rb + 32 + (lr * 2)) ^ sw))  = f2bf(p1);
          *(u16*)(Pbase + ((rb + 64 + (lr * 2)) ^ sw))  = f2bf(p2);
          *(u16*)(Pbase + ((rb + 96 + (lr * 2)) ^ sw))  = f2bf(p3);
        }
      }
      // --- PV from LDS ---
#pragma unroll
      for (int kf = 0; kf < 2; kf++) {
        s16x8 pf[2], vf[4];
#pragma unroll
        for (int m = 0; m < 2; m++) {
          int r = m * 16 + lr;
          pf[m] = *(const s16x8*)(Pbase + ((r * 128 + kf * 64 + lg * 16) ^ ((r & 7) << 4)));
        }
#pragma unroll
        for (int n = 0; n < 4; n++) {
          int r = n * 16 + lr;
          vf[n] = *(const s16x8*)(Vcur + (((r << 7) + kf * 64 + lg * 16) ^ ((r & 7) << 4)));
        }
#pragma unroll
        for (int m = 0; m < 2; m++)
#pragma unroll
          for (int n = 0; n < 4; n++)
            o[m][n] = __builtin_amdgcn_mfma_f32_16x16x32_bf16(pf[m], vf[n], o[m][n], 0, 0, 0);
      }
    }

    // write next tile into the other buffer (loads long since returned)
    if (pref) {
      char* dst = lds + (cur ^ 1) * BUF_STRIDE;
#pragma unroll
      for (int i = 0; i < 2; i++) {
        *(uint4*)(dst + KS_OFF + srow[i] * 128 + (scolb[i] ^ ssw[i])) = kd[i];
        *(uint4*)(dst + VS_OFF + srow[i] * 128 + (scolb[i] ^ ssw[i])) = vd[i];
      }
    }
    __syncthreads();
    cur ^= 1;
  }

  // epilogue: normalize + store [b][s][h*64+d]
#pragma unroll
  for (int m = 0; m < 2; m++)
#pragma unroll
    for (int v = 0; v < 4; v++) {
      int qq = q0 + m * 16 + lg * 4 + v;
      float inv = 1.0f / lrun[m][v];
#pragma unroll
      for (int n = 0; n < 4; n++)
        attout[(size_t)(b * SS + qq) * EE + h * DD + n * 16 + lr] = f2bf(o[m][n][v] * inv);
    }
}

extern "C" void kernel_launch(void* const* d_in, const int* in_sizes, int n_in,
                              void* d_out, int out_size, void* d_ws, size_t ws_size,
                              hipStream_t stream) {
  const float* query = (const float*)d_in[0];
  const float* key   = (const float*)d_in[1];
  const float* value = (const float*)d_in[2];
  const float* Wq = (const float*)d_in[3];
  const float* bq = (const float*)d_in[4];
  const float* Wk = (const float*)d_in[5];
  const float* bk = (const float*)d_in[6];
  const float* Wv = (const float*)d_in[7];
  const float* bv = (const float*)d_in[8];
  const float* Wo = (const float*)d_in[9];
  const float* bo = (const float*)d_in[10];
  const float* pb = (const float*)d_in[11];
  // idx0/idx1/mask are deterministic (rows/cols/triu) -> computed inline.

  char* ws = (char*)d_ws;
  u16* att  = (u16*)(ws + 0);                 // 16.78 MB (also scratch for bf16 inputs)
  u16* Wt3  = (u16*)(ws + 16777216);          // 6.29 MB (dead after projections)
  u16* Wot  = (u16*)(ws + 23068672);          // 2.10 MB
  u16* qp   = (u16*)(ws + 25165824);          // 16.78 MB  [b][h][s][d]
  u16* kp   = (u16*)(ws + 41943040);          // 16.78 MB
  u16* vT   = (u16*)(ws + 58720256);          // 16.78 MB  [b][h][d][s]
  u16* pbh  = Wt3;                            // 2 MB, overlays dead Wt3 region
  // total ws usage: 75,497,472 bytes (proven size)

  transpose_w<<<dim3(16, 16, 4), 256, 0, stream>>>(Wq, Wk, Wv, Wo, Wt3, Wot);

  // Projections: input converted f32->bf16 into `att` (scratch until attn_k),
  // serialized by stream order: convert X -> gemm X -> convert next (overwrite).
  f2h<<<dim3(4096), 256, 0, stream>>>(key, att);
  gemm128<<<dim3(8, 64), 256, 0, stream>>>(att, Wt3 + EE * EE, bk, kp, BB * SS, EE, EE, 1);
  f2h<<<dim3(4096), 256, 0, stream>>>(query, att);
  gemm128<<<dim3(8, 64), 256, 0, stream>>>(att, Wt3, bq, qp, BB * SS, EE, EE, 0);
  f2h<<<dim3(4096), 256, 0, stream>>>(value, att);
  gemm128<<<dim3(8, 64), 256, 0, stream>>>(att, Wt3 + 2 * EE * EE, bv, vT, BB * SS, EE, EE, 2);

  // Wt3 is dead from here; overwrite its first 2MB with the bf16 bias table.
  pb2h<<<dim3(SS * SS / 256), 256, 0, stream>>>(pb, pbh);

  attn_k<<<dim3(1024), 256, 0, stream>>>(qp, kp, vT, pbh, att);

  gemm128<<<dim3(8, 64), 256, 0, stream>>>(att, Wot, bo, d_out, BB * SS, EE, EE, 3);
}

// Round 16
// 227.636 us; speedup vs baseline: 1.1022x; 1.1022x over previous
//
#include <hip/hip_runtime.h>

typedef unsigned short u16;
typedef unsigned int u32;
typedef short s16x8 __attribute__((ext_vector_type(8)));
typedef float f32x4 __attribute__((ext_vector_type(4)));

// ---- constants for this problem ----
#define BB 8
#define SS 1024
#define EE 1024
#define HH 16
#define DD 64

__device__ inline u16 f2bf(float f) {
  union { float f; unsigned u; } x; x.f = f;
  unsigned r = x.u + 0x7fffu + ((x.u >> 16) & 1u);  // RNE
  return (u16)(r >> 16);
}
__device__ inline float bf2f(u16 u) {
  union { unsigned u; float f; } x; x.u = ((unsigned)u) << 16; return x.f;
}
// packed f32x2 -> bf16x2 via HW instruction (RNE), 1 VALU op
__device__ inline u32 cvtpk(float lo, float hi) {
  u32 r;
  asm("v_cvt_pk_bf16_f32 %0, %1, %2" : "=v"(r) : "v"(lo), "v"(hi));
  return r;
}

// ---------------- weight transpose+convert ----------------
__global__ __launch_bounds__(256) void transpose_w(
    const float* __restrict__ Wq, const float* __restrict__ Wk,
    const float* __restrict__ Wv, const float* __restrict__ Wo,
    u16* __restrict__ Wt3, u16* __restrict__ Wot)
{
  __shared__ float tile[64][65];
  int z = blockIdx.z;
  const float* src; u16* dst; int r0, c0, ldS, ldD;
  if (z < 3) {
    const float* W = (z == 0) ? Wq : (z == 1) ? Wk : Wv;
    int h = blockIdx.y;
    src = W + h * (EE * DD); r0 = blockIdx.x * 64; c0 = 0; ldS = DD;
    dst = Wt3 + z * (EE * EE) + h * 64 * EE; ldD = EE;
  } else {
    src = Wo; r0 = blockIdx.x * 64; c0 = blockIdx.y * 64; ldS = EE;
    dst = Wot; ldD = EE;
  }
  int t = threadIdx.x;
  int lr = t >> 2, lc = (t & 3) * 16;
#pragma unroll
  for (int i = 0; i < 16; i += 4) {
    float4 f = *(const float4*)(src + (size_t)(r0 + lr) * ldS + c0 + lc + i);
    tile[lr][lc + i] = f.x; tile[lr][lc + i + 1] = f.y;
    tile[lr][lc + i + 2] = f.z; tile[lr][lc + i + 3] = f.w;
  }
  __syncthreads();
#pragma unroll
  for (int i = 0; i < 16; i++)
    dst[(size_t)(c0 + lr) * ldD + r0 + lc + i] = f2bf(tile[lc + i][lr]);
}

// ---------------- pb -> bf16 table ----------------
__global__ __launch_bounds__(256) void pb2h(const float* __restrict__ pb,
                                            u16* __restrict__ pbh)
{
  int t = blockIdx.x * 256 + threadIdx.x;
  pbh[t] = f2bf(pb[t]);
}

// ---------------- f32 -> bf16 bulk convert (8 elems/thread) ----------------
__global__ __launch_bounds__(256) void f2h(const float* __restrict__ in,
                                           u16* __restrict__ out)
{
  int i = (blockIdx.x * 256 + threadIdx.x) * 8;
  float4 a = *(const float4*)(in + i);
  float4 b = *(const float4*)(in + i + 4);
  uint4 r;
  r.x = cvtpk(a.x, a.y); r.y = cvtpk(a.z, a.w);
  r.z = cvtpk(b.x, b.y); r.w = cvtpk(b.z, b.w);
  *(uint4*)(out + i) = r;
}

// ---------------- 128x128 bf16 GEMM: BK=64, BOTH operands via global_load_lds ----------------
// (r12-proven: ~690 TF on projections)
#define BK 64
__global__ __launch_bounds__(256, 2) void gemm128(
    const u16* __restrict__ At, const u16* __restrict__ Bt,
    const float* __restrict__ bias, void* __restrict__ out,
    int M, int N, int K, int mode)
{
  __shared__ __attribute__((aligned(16))) u16 As[128 * BK];
  __shared__ __attribute__((aligned(16))) u16 Bs[128 * BK];
  int t = threadIdx.x;
  int lane = t & 63, wid = t >> 6;
  int row0 = blockIdx.y * 128, col0 = blockIdx.x * 128;
  int wr = (wid >> 1) * 64, wc = (wid & 1) * 64;
  int lr = lane & 15, lg = lane >> 4;
  f32x4 acc[4][4];
#pragma unroll
  for (int m = 0; m < 4; m++)
#pragma unroll
    for (int n = 0; n < 4; n++)
      acc[m][n] = (f32x4){0.f, 0.f, 0.f, 0.f};

  int grow[4], gls[4];
#pragma unroll
  for (int j = 0; j < 4; j++) {
    int c = wid * 256 + j * 64 + lane;
    grow[j] = c >> 3;
    gls[j] = (c & 7) ^ (grow[j] & 7);
  }

  for (int k0 = 0; k0 < K; k0 += BK) {
    __syncthreads();
#pragma unroll
    for (int j = 0; j < 4; j++) {
      __builtin_amdgcn_global_load_lds(
          (const u32*)(At + (size_t)(row0 + grow[j]) * K + k0 + gls[j] * 8),
          (u32*)((char*)As + (wid * 256 + j * 64) * 16), 16, 0, 0);
      __builtin_amdgcn_global_load_lds(
          (const u32*)(Bt + (size_t)(col0 + grow[j]) * K + k0 + gls[j] * 8),
          (u32*)((char*)Bs + (wid * 256 + j * 64) * 16), 16, 0, 0);
    }
    __syncthreads();
#pragma unroll
    for (int kf = 0; kf < 2; kf++) {
      s16x8 af[4], bf[4];
#pragma unroll
      for (int m = 0; m < 4; m++) {
        int r = wr + m * 16 + lr;
        af[m] = *(const s16x8*)((char*)As + r * 128 + (((kf * 4 + lg) ^ (r & 7)) * 16));
      }
#pragma unroll
      for (int n = 0; n < 4; n++) {
        int r = wc + n * 16 + lr;
        bf[n] = *(const s16x8*)((char*)Bs + r * 128 + (((kf * 4 + lg) ^ (r & 7)) * 16));
      }
#pragma unroll
      for (int m = 0; m < 4; m++)
#pragma unroll
        for (int n = 0; n < 4; n++)
          acc[m][n] = __builtin_amdgcn_mfma_f32_16x16x32_bf16(af[m], bf[n], acc[m][n], 0, 0, 0);
    }
  }

#pragma unroll
  for (int n = 0; n < 4; n++) {
    int colb = col0 + wc + n * 16 + lr;
    float bv = bias[colb];
#pragma unroll
    for (int m = 0; m < 4; m++) {
#pragma unroll
      for (int v = 0; v < 4; v++) {
        int rowb = row0 + wr + m * 16 + lg * 4 + v;
        float val = acc[m][n][v] + bv;
        if (mode == 3) {
          ((float*)out)[(size_t)rowb * N + colb] = val;
        } else {
          int bb = rowb >> 10, s = rowb & 1023, hh = colb >> 6, dd = colb & 63;
          u16 u = f2bf(val);
          if (mode == 2)
            ((u16*)out)[(size_t)((bb * HH + hh) * DD + dd) * SS + s] = u;
          else
            ((u16*)out)[(size_t)((bb * HH + hh) * SS + s) * DD + dd] = u;
        }
      }
    }
  }
}

// ---------------- flash attention (v10: r14 body, K/V staged via global_load_lds) ----------------
// 1024 blocks x 256 threads. Decode: xcd = wgid&7, bh = xcd*16 + ((wgid>>3)&15),
// strip s = 7 - (wgid>>7). Block does 128 q rows, wave w owns rows q0b+32w..+32.
// K/V staged per 64-kv tile via global_load_lds width-16: LINEAR dest (chunk c
// -> byte c*16, c = wid*128 + i*64 + lane), INVERSE-swizzled source slot
// (c&7)^(row&7)  (rule-#21; identical mapping to r12's gemm128, reads keep the
// r7-proven XOR). Zero registers held across compute (r13/r15 lesson).
// LDS 32KB; softmax/PV byte-identical to r14.
#define KVB 64
#define KS_OFF 0
#define VS_OFF 8192
#define PW_OFF 16384

__global__ __launch_bounds__(256) void attn_k(
    const u16* __restrict__ qp, const u16* __restrict__ kp,
    const u16* __restrict__ vT, const u16* __restrict__ pbh,
    u16* __restrict__ attout)
{
  __shared__ __attribute__((aligned(16))) char lds[32768];
  int wgid = blockIdx.x;
  int bh = (wgid & 7) * 16 + ((wgid >> 3) & 15);
  int s8 = 7 - (wgid >> 7);
  int t = threadIdx.x;
  int lane = t & 63, wid = t >> 6;
  int lr = lane & 15, lg = lane >> 4;
  const char* Qb = (const char*)(qp + (size_t)bh * SS * DD);
  const char* Kb = (const char*)(kp + (size_t)bh * SS * DD);
  const char* Vb = (const char*)(vT + (size_t)bh * SS * DD);
  int b = bh >> 4, h = bh & 15;
  char* Pbase = lds + PW_OFF + wid * 4096;

  int q0b = s8 * 128;
  int q0 = q0b + wid * 32;
  int kv_end = q0 + 32;

  // gll chunk assignment (2 chunks/thread, wave-contiguous)
  int crow[2], cgls[2], cbase[2];
#pragma unroll
  for (int i = 0; i < 2; i++) {
    int c = wid * 128 + i * 64 + lane;
    crow[i] = c >> 3;
    cgls[i] = (c & 7) ^ (crow[i] & 7);
    cbase[i] = (wid * 128 + i * 64) * 16;   // wave-uniform LDS byte base
  }

  // Q fragments for this strip
  s16x8 qf[2][2];
#pragma unroll
  for (int m = 0; m < 2; m++)
#pragma unroll
    for (int kf = 0; kf < 2; kf++)
      qf[m][kf] = *(const s16x8*)(Qb + (size_t)(q0 + m * 16 + lr) * 128 + kf * 64 + lg * 16);

  f32x4 o[2][4];
  float mrun[2][4], lrun[2][4];
#pragma unroll
  for (int m = 0; m < 2; m++) {
#pragma unroll
    for (int n = 0; n < 4; n++) o[m][n] = (f32x4){0.f, 0.f, 0.f, 0.f};
#pragma unroll
    for (int v = 0; v < 4; v++) { mrun[m][v] = -1e30f; lrun[m][v] = 0.f; }
  }

  for (int kv0 = 0; kv0 < q0b + 128; kv0 += KVB) {
    // ---- stage K, V^T tiles via global_load_lds (no regs, no in-line waits) ----
#pragma unroll
    for (int i = 0; i < 2; i++) {
      __builtin_amdgcn_global_load_lds(
          (const u32*)(Kb + (size_t)(kv0 + crow[i]) * 128 + cgls[i] * 16),
          (u32*)(lds + KS_OFF + cbase[i]), 16, 0, 0);
      __builtin_amdgcn_global_load_lds(
          (const u32*)(Vb + (size_t)crow[i] * 2048 + (size_t)kv0 * 2 + cgls[i] * 16),
          (u32*)(lds + VS_OFF + cbase[i]), 16, 0, 0);
    }
    __syncthreads();

    if (kv0 < kv_end) {
      // --- QK^T from LDS ---
      f32x4 s[2][4];
#pragma unroll
      for (int tt = 0; tt < 4; tt++) {
        int r = tt * 16 + lr;
        int sw = (r & 7) << 4;
        s16x8 k0 = *(const s16x8*)(lds + KS_OFF + (((r << 7) + lg * 16) ^ sw));
        s16x8 k1 = *(const s16x8*)(lds + KS_OFF + (((r << 7) + 64 + lg * 16) ^ sw));
#pragma unroll
        for (int m = 0; m < 2; m++) {
          f32x4 acc = (f32x4){0.f, 0.f, 0.f, 0.f};
          acc = __builtin_amdgcn_mfma_f32_16x16x32_bf16(qf[m][0], k0, acc, 0, 0, 0);
          acc = __builtin_amdgcn_mfma_f32_16x16x32_bf16(qf[m][1], k1, acc, 0, 0, 0);
          s[m][tt] = acc;
        }
      }
      bool full = (kv0 + KVB - 1 <= q0);
      // --- scale + bias + causal + online softmax (one-pass, __expf) ---
#pragma unroll
      for (int m = 0; m < 2; m++) {
#pragma unroll
        for (int v = 0; v < 4; v++) {
          int qq = q0 + m * 16 + lg * 4 + v;
          const u16* pbrow = pbh + (size_t)qq * SS + kv0 + lr;
          float sv[4];
#pragma unroll
          for (int tt = 0; tt < 4; tt++) {
            float bi = bf2f(pbrow[tt * 16]);
            float x = fmaf(s[m][tt][v], 0.125f, bi);
            if (!full && (kv0 + tt * 16 + lr > qq)) x = -1e30f;
            sv[tt] = x;
          }
          float mt = fmaxf(fmaxf(sv[0], sv[1]), fmaxf(sv[2], sv[3]));
          mt = fmaxf(mt, __shfl_xor(mt, 1));
          mt = fmaxf(mt, __shfl_xor(mt, 2));
          mt = fmaxf(mt, __shfl_xor(mt, 4));
          mt = fmaxf(mt, __shfl_xor(mt, 8));
          float mn = fmaxf(mrun[m][v], mt);
          float corr = __expf(mrun[m][v] - mn);
          float p0 = __expf(sv[0] - mn);
          float p1 = __expf(sv[1] - mn);
          float p2 = __expf(sv[2] - mn);
          float p3 = __expf(sv[3] - mn);
          float rs = (p0 + p1) + (p2 + p3);
          rs += __shfl_xor(rs, 1);
          rs += __shfl_xor(rs, 2);
          rs += __shfl_xor(rs, 4);
          rs += __shfl_xor(rs, 8);
          lrun[m][v] = lrun[m][v] * corr + rs;
          mrun[m][v] = mn;
#pragma unroll
          for (int n = 0; n < 4; n++) o[m][n][v] *= corr;
          int qrow = m * 16 + lg * 4 + v;
          int rb = qrow * 128;
          int sw = (qrow & 7) << 4;
          *(u16*)(Pbase + ((rb + (lr * 2)) ^ sw))       = f2bf(p0);
          *(u16*)(Pbase + ((rb + 32 + (lr * 2)) ^ sw))  = f2bf(p1);
          *(u16*)(Pbase + ((rb + 64 + (lr * 2)) ^ sw))  = f2bf(p2);
          *(u16*)(Pbase + ((rb + 96 + (lr * 2)) ^ sw))  = f2bf(p3);
        }
      }
      // --- PV from LDS ---
#pragma unroll
      for (int kf = 0; kf < 2; kf++) {
        s16x8 pf[2], vf[4];
#pragma unroll
        for (int m = 0; m < 2; m++) {
          int r = m * 16 + lr;
          pf[m] = *(const s16x8*)(Pbase + ((r * 128 + kf * 64 + lg * 16) ^ ((r & 7) << 4)));
        }
#pragma unroll
        for (int n = 0; n < 4; n++) {
          int r = n * 16 + lr;
          vf[n] = *(const s16x8*)(lds + VS_OFF + (((r << 7) + kf * 64 + lg * 16) ^ ((r & 7) << 4)));
        }
#pragma unroll
        for (int m = 0; m < 2; m++)
#pragma unroll
          for (int n = 0; n < 4; n++)
            o[m][n] = __builtin_amdgcn_mfma_f32_16x16x32_bf16(pf[m], vf[n], o[m][n], 0, 0, 0);
      }
    }
    __syncthreads();
  }

  // epilogue: normalize + store [b][s][h*64+d]
#pragma unroll
  for (int m = 0; m < 2; m++)
#pragma unroll
    for (int v = 0; v < 4; v++) {
      int qq = q0 + m * 16 + lg * 4 + v;
      float inv = 1.0f / lrun[m][v];
#pragma unroll
      for (int n = 0; n < 4; n++)
        attout[(size_t)(b * SS + qq) * EE + h * DD + n * 16 + lr] = f2bf(o[m][n][v] * inv);
    }
}

extern "C" void kernel_launch(void* const* d_in, const int* in_sizes, int n_in,
                              void* d_out, int out_size, void* d_ws, size_t ws_size,
                              hipStream_t stream) {
  const float* query = (const float*)d_in[0];
  const float* key   = (const float*)d_in[1];
  const float* value = (const float*)d_in[2];
  const float* Wq = (const float*)d_in[3];
  const float* bq = (const float*)d_in[4];
  const float* Wk = (const float*)d_in[5];
  const float* bk = (const float*)d_in[6];
  const float* Wv = (const float*)d_in[7];
  const float* bv = (const float*)d_in[8];
  const float* Wo = (const float*)d_in[9];
  const float* bo = (const float*)d_in[10];
  const float* pb = (const float*)d_in[11];
  // idx0/idx1/mask are deterministic (rows/cols/triu) -> computed inline.

  char* ws = (char*)d_ws;
  u16* att  = (u16*)(ws + 0);                 // 16.78 MB (also scratch for bf16 inputs)
  u16* Wt3  = (u16*)(ws + 16777216);          // 6.29 MB (dead after projections)
  u16* Wot  = (u16*)(ws + 23068672);          // 2.10 MB
  u16* qp   = (u16*)(ws + 25165824);          // 16.78 MB  [b][h][s][d]
  u16* kp   = (u16*)(ws + 41943040);          // 16.78 MB
  u16* vT   = (u16*)(ws + 58720256);          // 16.78 MB  [b][h][d][s]
  u16* pbh  = Wt3;                            // 2 MB, overlays dead Wt3 region
  // total ws usage: 75,497,472 bytes (proven size)

  transpose_w<<<dim3(16, 16, 4), 256, 0, stream>>>(Wq, Wk, Wv, Wo, Wt3, Wot);

  // Projections: input converted f32->bf16 into `att` (scratch until attn_k),
  // serialized by stream order: convert X -> gemm X -> convert next (overwrite).
  f2h<<<dim3(4096), 256, 0, stream>>>(key, att);
  gemm128<<<dim3(8, 64), 256, 0, stream>>>(att, Wt3 + EE * EE, bk, kp, BB * SS, EE, EE, 1);
  f2h<<<dim3(4096), 256, 0, stream>>>(query, att);
  gemm128<<<dim3(8, 64), 256, 0, stream>>>(att, Wt3, bq, qp, BB * SS, EE, EE, 0);
  f2h<<<dim3(4096), 256, 0, stream>>>(value, att);
  gemm128<<<dim3(8, 64), 256, 0, stream>>>(att, Wt3 + 2 * EE * EE, bv, vT, BB * SS, EE, EE, 2);

  // Wt3 is dead from here; overwrite its first 2MB with the bf16 bias table.
  pb2h<<<dim3(SS * SS / 256), 256, 0, stream>>>(pb, pbh);

  attn_k<<<dim3(1024), 256, 0, stream>>>(qp, kp, vT, pbh, att);

  gemm128<<<dim3(8, 64), 256, 0, stream>>>(att, Wot, bo, d_out, BB * SS, EE, EE, 3);
}